// Round 5
// baseline (152.859 us; speedup 1.0000x reference)
//
#include <hip/hip_runtime.h>
#include <math.h>
#include <stdint.h>

// Problem constants (fixed by setup_inputs)
#define E_EDGES 16384
#define H_DIM   256
#define S_SEEDS 32
#define NHEADS  8
#define HDIM    32
#define BGRAPHS 16
#define EPG     1024
#define NCHUNK  256       // 64-edge chunks
#define CPG     16        // chunks per graph
#define RSQRT_HD 0.17677669529663687f

typedef __attribute__((ext_vector_type(8))) short bf16x8;   // 8 bf16 (4 VGPRs)
typedef __attribute__((ext_vector_type(4))) float f32x4;

__device__ inline unsigned short f2bf(float x) {            // round-to-nearest-even
    unsigned u = __float_as_uint(x);
    u += 0x7fff + ((u >> 16) & 1);
    return (unsigned short)(u >> 16);
}
__device__ inline float bf2f(unsigned int h) {
    return __uint_as_float((h & 0xffffu) << 16);
}
__device__ inline unsigned pack2(float a, float b) {
    return (unsigned)f2bf(a) | ((unsigned)f2bf(b) << 16);
}

// ---------------- K1: WcT[n][k] bf16, n<256: Wv col, n>=256: folded q@Wk score col
__global__ __launch_bounds__(256) void k_wc(const float* __restrict__ Wv,
                                            const float* __restrict__ Wk,
                                            const float* __restrict__ Wq,
                                            const float* __restrict__ seed,
                                            unsigned short* __restrict__ WcT) {
    int j = blockIdx.x;          // 0..511 output row (n), block-uniform
    int i = threadIdx.x;         // 0..255 (k index)
    float val;
    if (j < H_DIM) {
        val = Wv[i * H_DIM + j];
    } else {
        int c = j - H_DIM;
        int h = c >> 5, s = c & 31;
        __shared__ float qp[8][33];
        __shared__ float qrow[HDIM];
        int d = i & 31, g = i >> 5;
        const float* wq = &Wq[(g * 32) * H_DIM + h * HDIM + d];
        const float* sd = &seed[s * H_DIM + g * 32];
        float p = 0.f;
        #pragma unroll
        for (int ii = 0; ii < 32; ++ii)
            p = fmaf(sd[ii], wq[(size_t)ii * H_DIM], p);
        qp[g][d] = p;
        __syncthreads();
        if (i < HDIM) {
            float qv = 0.f;
            #pragma unroll
            for (int g2 = 0; g2 < 8; ++g2) qv += qp[g2][i];
            qrow[i] = qv;
        }
        __syncthreads();
        const float* wk = &Wk[i * H_DIM + h * HDIM];
        float acc = 0.f;
        #pragma unroll
        for (int dd = 0; dd < HDIM; dd += 4) {
            float4 w = *(const float4*)&wk[dd];
            float4 qq = *(const float4*)&qrow[dd];
            acc = fmaf(w.x, qq.x, acc); acc = fmaf(w.y, qq.y, acc);
            acc = fmaf(w.z, qq.z, acc); acc = fmaf(w.w, qq.w, acc);
        }
        val = acc * RSQRT_HD;
    }
    WcT[j * H_DIM + i] = f2bf(val);
}

// ---------------- K2: fused attention per 64-edge chunk, 512 threads ----------------
// half = tid>>8 processes tiles {V_half, S_half} (heads half*4..half*4+3).
// A-tile shared; per-half Bs dbuf (Pt aliases it: disjoint lifetimes);
// per-half Vt. 113 KB LDS, 1 block/CU, 8 waves/CU (2/SIMD).
struct HalfBuf {
    union {
        unsigned short Bs[2][128][40];   // 20480 B k-slice dbuf
        unsigned short Pt[128][72];      // 18432 B P transposed [col][e]
    };
};
struct SMattn {
    unsigned short As[64][264];          // 33792 B (528B row stride, 16B-aligned)
    HalfBuf hb[2];                       // 40960 B
    unsigned short Vt[2][128][72];       // 36864 B V transposed [d_local][e]
    float smx[2][2][128];                //  2048 B
    float ssm[2][2][128];                //  2048 B
};                                       // = 115712 B

__global__ __launch_bounds__(512) void k_attn(const float* __restrict__ A,
                                              const unsigned short* __restrict__ WcT,
                                              float* __restrict__ outc,
                                              float* __restrict__ mg,
                                              float* __restrict__ sg) {
    __shared__ SMattn sm;
    int tid = threadIdx.x;
    int chunk = blockIdx.x;
    int e0 = chunk * 64;
    int half = tid >> 8;                 // 0/1: tile-half
    int tl = tid & 255;                  // local tid within half
    int w4 = tl >> 6, lane = tid & 63;
    int lr = lane & 15, kg = lane >> 4;
    int wm = (w4 & 1) * 32, wn = (w4 >> 1) * 64;

    {   // A prologue: 64x256 fp32 -> bf16 LDS, all 512 threads
        int r = tid >> 3, cg8 = tid & 7;
        const float* ap = &A[(size_t)(e0 + r) * H_DIM + cg8 * 32];
        #pragma unroll
        for (int i = 0; i < 4; ++i) {
            float4 x = *(const float4*)&ap[i * 8];
            float4 y = *(const float4*)&ap[i * 8 + 4];
            uint4 o;
            o.x = pack2(x.x, x.y); o.y = pack2(x.z, x.w);
            o.z = pack2(y.x, y.y); o.w = pack2(y.z, y.w);
            *(uint4*)&sm.As[r][cg8 * 32 + i * 8] = o;
        }
    }
    int brow = tl >> 1, bhalf16 = (tl & 1) * 16;
    f32x4 acc2[2][2] = {};               // PV accum [ms][nd]
    uint4 pb0, pb1;
    {   // preload t2=0 (V tile of this half), k=0
        const unsigned short* bp = &WcT[(size_t)(half * 128 + brow) * H_DIM + bhalf16];
        pb0 = *(const uint4*)bp; pb1 = *(const uint4*)(bp + 8);
    }
    #pragma unroll
    for (int t2 = 0; t2 < 2; ++t2) {     // t2=0: V tile, t2=1: S tile
        f32x4 acc[2][4] = {};            // [mi][ni]
        #pragma unroll
        for (int k = 0; k < 8; ++k) {
            *(uint4*)&sm.hb[half].Bs[k & 1][brow][bhalf16]     = pb0;
            *(uint4*)&sm.hb[half].Bs[k & 1][brow][bhalf16 + 8] = pb1;
            __syncthreads();             // prior frag reads done + this slice visible
            int nk = k + 1, nt2 = t2;
            if (nk == 8) { nk = 0; nt2 = t2 + 1; }
            if (nt2 < 2) {               // WcT row block: half*128 + t2*256
                const unsigned short* bp =
                    &WcT[(size_t)(half * 128 + nt2 * 256 + brow) * H_DIM + nk * 32 + bhalf16];
                pb0 = *(const uint4*)bp; pb1 = *(const uint4*)(bp + 8);
            }
            bf16x8 af[2], bfv[4];
            #pragma unroll
            for (int mi = 0; mi < 2; ++mi)
                af[mi] = *(const bf16x8*)&sm.As[wm + mi * 16 + lr][k * 32 + kg * 8];
            #pragma unroll
            for (int ni = 0; ni < 4; ++ni)
                bfv[ni] = *(const bf16x8*)&sm.hb[half].Bs[k & 1][wn + ni * 16 + lr][kg * 8];
            #pragma unroll
            for (int mi = 0; mi < 2; ++mi)
                #pragma unroll
                for (int ni = 0; ni < 4; ++ni)
                    acc[mi][ni] = __builtin_amdgcn_mfma_f32_16x16x32_bf16(
                        af[mi], bfv[ni], acc[mi][ni], 0, 0, 0);
        }
        if (t2 == 0) {
            // V epilogue: acc(e, d_local) -> Vt[half][d_local][e] bf16
            #pragma unroll
            for (int mi = 0; mi < 2; ++mi)
                #pragma unroll
                for (int ni = 0; ni < 4; ++ni)
                    #pragma unroll
                    for (int r = 0; r < 4; ++r)
                        sm.Vt[half][wn + ni * 16 + lr][wm + mi * 16 + kg * 4 + r] =
                            f2bf(acc[mi][ni][r]);
            // visibility guaranteed by t2=1 k-loop barriers before PV reads
        } else {
            // S epilogue: chunk softmax (fp32 scores, bf16 P) + PV MFMA
            float tmax[4];
            #pragma unroll
            for (int ni = 0; ni < 4; ++ni) {
                float m = -1e30f;
                #pragma unroll
                for (int mi = 0; mi < 2; ++mi)
                    #pragma unroll
                    for (int r = 0; r < 4; ++r) m = fmaxf(m, acc[mi][ni][r]);
                m = fmaxf(m, __shfl_xor(m, 16, 64));
                m = fmaxf(m, __shfl_xor(m, 32, 64));
                tmax[ni] = m;
            }
            if (kg == 0) {
                #pragma unroll
                for (int ni = 0; ni < 4; ++ni)
                    sm.smx[half][w4 & 1][wn + ni * 16 + lr] = tmax[ni];
            }
            __syncthreads();             // also: all Bs[1] k=7 frag reads done -> Pt alias safe
            float tsum[4];
            #pragma unroll
            for (int ni = 0; ni < 4; ++ni) {
                int col = wn + ni * 16 + lr;
                float m = fmaxf(sm.smx[half][0][col], sm.smx[half][1][col]);
                float sv = 0.f;
                #pragma unroll
                for (int mi = 0; mi < 2; ++mi)
                    #pragma unroll
                    for (int r = 0; r < 4; ++r) {
                        float e_ = __expf(acc[mi][ni][r] - m);
                        unsigned short eb = f2bf(e_);
                        sm.hb[half].Pt[col][wm + mi * 16 + kg * 4 + r] = eb;
                        sv += bf2f(eb);
                    }
                sv += __shfl_xor(sv, 16, 64);
                sv += __shfl_xor(sv, 32, 64);
                tsum[ni] = sv;
            }
            if (kg == 0) {
                #pragma unroll
                for (int ni = 0; ni < 4; ++ni)
                    sm.ssm[half][w4 & 1][wn + ni * 16 + lr] = tsum[ni];
            }
            __syncthreads();             // Pt + ssm visible
            if (tl < 128) {
                float m = fmaxf(sm.smx[half][0][tl], sm.smx[half][1][tl]);
                float sv = sm.ssm[half][0][tl] + sm.ssm[half][1][tl];
                mg[(size_t)chunk * H_DIM + half * 128 + tl] = m;
                sg[(size_t)chunk * H_DIM + half * 128 + tl] = sv;
            }
            // PV: wave w4 handles head h = half*4 + w4
            #pragma unroll
            for (int ms = 0; ms < 2; ++ms)
                #pragma unroll
                for (int nd = 0; nd < 2; ++nd)
                    #pragma unroll
                    for (int kk = 0; kk < 2; ++kk) {
                        bf16x8 pa = *(const bf16x8*)
                            &sm.hb[half].Pt[w4 * 32 + ms * 16 + lr][kk * 32 + kg * 8];
                        bf16x8 vb = *(const bf16x8*)
                            &sm.Vt[half][w4 * 32 + nd * 16 + lr][kk * 32 + kg * 8];
                        acc2[ms][nd] = __builtin_amdgcn_mfma_f32_16x16x32_bf16(
                            pa, vb, acc2[ms][nd], 0, 0, 0);
                    }
        }
    }
    // store chunk partial: outc[chunk][s][h*32+d] fp32
    #pragma unroll
    for (int ms = 0; ms < 2; ++ms)
        #pragma unroll
        for (int nd = 0; nd < 2; ++nd)
            #pragma unroll
            for (int r = 0; r < 4; ++r) {
                int s_ = ms * 16 + kg * 4 + r;
                int c_ = (half * 4 + w4) * 32 + nd * 16 + lr;
                outc[((size_t)chunk * 32 + s_) * H_DIM + c_] = acc2[ms][nd][r];
            }
}

// ---------------- block reduction helper (256 threads = 4 waves) ----------------
__device__ inline float block_sum256(float v, float* red4) {
    for (int o = 32; o > 0; o >>= 1) v += __shfl_xor(v, o, 64);
    int wid = threadIdx.x >> 6;
    if ((threadIdx.x & 63) == 0) red4[wid] = v;
    __syncthreads();
    float r = red4[0] + red4[1] + red4[2] + red4[3];
    __syncthreads();
    return r;
}

// ---------------- K3: flash combine + y = LN(seed + att @ Wo + bo) ----------------
__global__ __launch_bounds__(256) void k_proj_ln(const float* __restrict__ outc,
                                                 const float* __restrict__ mg,
                                                 const float* __restrict__ sg,
                                                 const float* __restrict__ seed,
                                                 const float* __restrict__ Wo,
                                                 const float* __restrict__ bo,
                                                 const float* __restrict__ ln_g,
                                                 const float* __restrict__ ln_b,
                                                 float* __restrict__ Y) {
    int bs0 = blockIdx.x * 4;             // 4 rows, same graph b
    int c = threadIdx.x;
    int b = bs0 >> 5;
    __shared__ float sscale[4][CPG][8];   // exp(m_j - M)/Den per (row, chunk, head)
    __shared__ float arow[4][H_DIM];
    __shared__ float red4[4];
    if (c < 32) {
        int r = c >> 3, hh = c & 7;
        int s_r = (bs0 + r) & 31;
        int sc = hh * 32 + s_r;           // score col for (s,h)
        float mj[CPG];
        float M = -1e30f;
        #pragma unroll
        for (int j = 0; j < CPG; ++j) {
            mj[j] = mg[(size_t)(b * CPG + j) * H_DIM + sc];
            M = fmaxf(M, mj[j]);
        }
        float Den = 0.f;
        #pragma unroll
        for (int j = 0; j < CPG; ++j)
            Den += sg[(size_t)(b * CPG + j) * H_DIM + sc] * __expf(mj[j] - M);
        float inv = 1.f / Den;
        #pragma unroll
        for (int j = 0; j < CPG; ++j)
            sscale[r][j][hh] = __expf(mj[j] - M) * inv;
    }
    __syncthreads();
    int h = c >> 5;
    #pragma unroll
    for (int r = 0; r < 4; ++r) {
        int s_r = (bs0 + r) & 31;
        float a = 0.f;
        #pragma unroll
        for (int j = 0; j < CPG; ++j)
            a = fmaf(outc[((size_t)(b * CPG + j) * 32 + s_r) * H_DIM + c],
                     sscale[r][j][h], a);
        arow[r][c] = a;
    }
    __syncthreads();
    float acc[4];
    float b0 = bo[c];
    #pragma unroll
    for (int r = 0; r < 4; ++r) acc[r] = b0;
    for (int i = 0; i < H_DIM; i += 4) {
        float4 a0 = *(const float4*)&arow[0][i];
        float4 a1 = *(const float4*)&arow[1][i];
        float4 a2 = *(const float4*)&arow[2][i];
        float4 a3 = *(const float4*)&arow[3][i];
        float w0 = Wo[(i + 0) * H_DIM + c], w1 = Wo[(i + 1) * H_DIM + c];
        float w2 = Wo[(i + 2) * H_DIM + c], w3 = Wo[(i + 3) * H_DIM + c];
        acc[0] = fmaf(a0.x, w0, acc[0]); acc[0] = fmaf(a0.y, w1, acc[0]);
        acc[0] = fmaf(a0.z, w2, acc[0]); acc[0] = fmaf(a0.w, w3, acc[0]);
        acc[1] = fmaf(a1.x, w0, acc[1]); acc[1] = fmaf(a1.y, w1, acc[1]);
        acc[1] = fmaf(a1.z, w2, acc[1]); acc[1] = fmaf(a1.w, w3, acc[1]);
        acc[2] = fmaf(a2.x, w0, acc[2]); acc[2] = fmaf(a2.y, w1, acc[2]);
        acc[2] = fmaf(a2.z, w2, acc[2]); acc[2] = fmaf(a2.w, w3, acc[2]);
        acc[3] = fmaf(a3.x, w0, acc[3]); acc[3] = fmaf(a3.y, w1, acc[3]);
        acc[3] = fmaf(a3.z, w2, acc[3]); acc[3] = fmaf(a3.w, w3, acc[3]);
    }
    float g = ln_g[c], be = ln_b[c];
    #pragma unroll
    for (int r = 0; r < 4; ++r) {
        int bs = bs0 + r;
        float y = seed[(bs & 31) * H_DIM + c] + acc[r];
        float mu = block_sum256(y, red4) * (1.f / 256.f);
        float d = y - mu;
        float var = block_sum256(d * d, red4) * (1.f / 256.f);
        Y[(size_t)bs * H_DIM + c] = d * rsqrtf(var + 1e-5f) * g + be;
    }
}

// ---------------- K4: MLP1 partials, W1 read exactly once ----------------
__global__ __launch_bounds__(256) void k_mlp1(const float* __restrict__ Y,
                                              const float* __restrict__ W1,
                                              float* __restrict__ part) {
    int ch = blockIdx.x;          // 128 chunks x 64 rows of W1
    int c = threadIdx.x;
    int i0 = ch * 64;
    __shared__ float fbuf[16][64];
    #pragma unroll
    for (int it = 0; it < 4; ++it) {
        int li = it * 256 + c;
        fbuf[li >> 6][li & 63] = Y[(size_t)(li >> 6) * 8192 + i0 + (li & 63)];
    }
    __syncthreads();
    float acc[16];
    #pragma unroll
    for (int b = 0; b < 16; ++b) acc[b] = 0.f;
    for (int ii = 0; ii < 64; ++ii) {
        float w = W1[(size_t)(i0 + ii) * H_DIM + c];
        #pragma unroll
        for (int b = 0; b < 16; ++b) acc[b] = fmaf(fbuf[b][ii], w, acc[b]);
    }
    #pragma unroll
    for (int b = 0; b < 16; ++b)
        part[((size_t)b * 128 + ch) * H_DIM + c] = acc[b];
}

// ---------------- K5: reduce + SiLU + @W2 + b2 ----------------
__global__ __launch_bounds__(256) void k_mlp2(const float* __restrict__ part,
                                              const float* __restrict__ b1,
                                              const float* __restrict__ W2,
                                              const float* __restrict__ b2,
                                              float* __restrict__ out) {
    int b = blockIdx.x;
    int c = threadIdx.x;
    float s = b1[c];
    const float* pb = &part[(size_t)b * 128 * H_DIM + c];
    #pragma unroll 4
    for (int ch = 0; ch < 128; ++ch) s += pb[(size_t)ch * H_DIM];
    float h1 = s / (1.f + __expf(-s));
    __shared__ float hrow[H_DIM];
    hrow[c] = h1;
    __syncthreads();
    float acc = b2[c];
    for (int j = 0; j < H_DIM; j += 4) {
        float4 hq = *(const float4*)&hrow[j];
        acc = fmaf(hq.x, W2[(j + 0) * H_DIM + c], acc);
        acc = fmaf(hq.y, W2[(j + 1) * H_DIM + c], acc);
        acc = fmaf(hq.z, W2[(j + 2) * H_DIM + c], acc);
        acc = fmaf(hq.w, W2[(j + 3) * H_DIM + c], acc);
    }
    out[(size_t)b * H_DIM + c] = acc;
}

extern "C" void kernel_launch(void* const* d_in, const int* in_sizes, int n_in,
                              void* d_out, int out_size, void* d_ws, size_t ws_size,
                              hipStream_t stream) {
    const float* edge_features = (const float*)d_in[0];
    const float* seed = (const float*)d_in[3];
    const float* Wq   = (const float*)d_in[4];
    const float* Wk   = (const float*)d_in[5];
    const float* Wv   = (const float*)d_in[6];
    const float* Wo   = (const float*)d_in[7];
    const float* bo   = (const float*)d_in[8];
    const float* ln_g = (const float*)d_in[9];
    const float* ln_b = (const float*)d_in[10];
    const float* W1   = (const float*)d_in[11];
    const float* b1   = (const float*)d_in[12];
    const float* W2   = (const float*)d_in[13];
    const float* b2   = (const float*)d_in[14];
    float* out = (float*)d_out;

    // Workspace layout (floats)
    float* ws = (float*)d_ws;
    unsigned short* WcT = (unsigned short*)ws;                    // 512*256 u16 (65536 f)
    float* outc = ws + 65536;                                     // 256*32*256 = 2097152
    float* mg   = outc + 2097152;                                 // 256*256 = 65536
    float* sg   = mg + 65536;                                     // 65536
    float* Y    = sg + 65536;                                     // 131072
    float* part = Y + 131072;                                     // 524288
    // total ~= 2.95M floats ~= 11.8 MB

    k_wc      <<<512, 256, 0, stream>>>(Wv, Wk, Wq, seed, WcT);
    k_attn    <<<NCHUNK, 512, 0, stream>>>(edge_features, WcT, outc, mg, sg);
    k_proj_ln <<<BGRAPHS * S_SEEDS / 4, 256, 0, stream>>>(outc, mg, sg, seed, Wo, bo, ln_g, ln_b, Y);
    k_mlp1    <<<128, 256, 0, stream>>>(Y, W1, part);
    k_mlp2    <<<BGRAPHS, 256, 0, stream>>>(part, b1, W2, b2, out);
}

// Round 6
// 149.788 us; speedup vs baseline: 1.0205x; 1.0205x over previous
//
#include <hip/hip_runtime.h>
#include <math.h>
#include <stdint.h>

// Problem constants (fixed by setup_inputs)
#define E_EDGES 16384
#define H_DIM   256
#define S_SEEDS 32
#define NHEADS  8
#define HDIM    32
#define BGRAPHS 16
#define EPG     1024
#define NCHUNK  256       // 64-edge chunks
#define CPG     16        // chunks per graph
#define RSQRT_HD 0.17677669529663687f

typedef __attribute__((ext_vector_type(8))) short bf16x8;   // 8 bf16 (4 VGPRs)
typedef __attribute__((ext_vector_type(4))) float f32x4;

__device__ inline unsigned short f2bf(float x) {            // round-to-nearest-even
    unsigned u = __float_as_uint(x);
    u += 0x7fff + ((u >> 16) & 1);
    return (unsigned short)(u >> 16);
}
__device__ inline float bf2f(unsigned int h) {
    return __uint_as_float((h & 0xffffu) << 16);
}
__device__ inline unsigned pack2(float a, float b) {
    return (unsigned)f2bf(a) | ((unsigned)f2bf(b) << 16);
}

// ---------------- K1: WcT[n][k] bf16, n<256: Wv col, n>=256: folded q@Wk score col
__global__ __launch_bounds__(256) void k_wc(const float* __restrict__ Wv,
                                            const float* __restrict__ Wk,
                                            const float* __restrict__ Wq,
                                            const float* __restrict__ seed,
                                            unsigned short* __restrict__ WcT) {
    int j = blockIdx.x;          // 0..511 output row (n), block-uniform
    int i = threadIdx.x;         // 0..255 (k index)
    float val;
    if (j < H_DIM) {
        val = Wv[i * H_DIM + j];
    } else {
        int c = j - H_DIM;
        int h = c >> 5, s = c & 31;
        __shared__ float qp[8][33];
        __shared__ float qrow[HDIM];
        int d = i & 31, g = i >> 5;
        const float* wq = &Wq[(g * 32) * H_DIM + h * HDIM + d];
        const float* sd = &seed[s * H_DIM + g * 32];
        float p = 0.f;
        #pragma unroll
        for (int ii = 0; ii < 32; ++ii)
            p = fmaf(sd[ii], wq[(size_t)ii * H_DIM], p);
        qp[g][d] = p;
        __syncthreads();
        if (i < HDIM) {
            float qv = 0.f;
            #pragma unroll
            for (int g2 = 0; g2 < 8; ++g2) qv += qp[g2][i];
            qrow[i] = qv;
        }
        __syncthreads();
        const float* wk = &Wk[i * H_DIM + h * HDIM];
        float acc = 0.f;
        #pragma unroll
        for (int dd = 0; dd < HDIM; dd += 4) {
            float4 w = *(const float4*)&wk[dd];
            float4 qq = *(const float4*)&qrow[dd];
            acc = fmaf(w.x, qq.x, acc); acc = fmaf(w.y, qq.y, acc);
            acc = fmaf(w.z, qq.z, acc); acc = fmaf(w.w, qq.w, acc);
        }
        val = acc * RSQRT_HD;
    }
    WcT[j * H_DIM + i] = f2bf(val);
}

// ---------------- K2: fused attention per 64-edge chunk, 512 threads ----------------
// Free-running schedule: stage A -> bar -> each wave owns a full 64-col slice
// (B-frags loaded DIRECTLY from L2-resident WcT, 2-deep register prefetch,
// no Bs staging, no per-k barriers) -> in-wave column softmax -> Vt/Pt
// scatter -> bar -> PV MFMA -> store. 2 barriers total.
struct SMattn {
    unsigned short As[64][264];          // 33792 B (528B row stride)
    unsigned short Vt[256][72];          // 36864 B  V transposed [d][e]
    unsigned short Pt[256][72];          // 36864 B  P transposed [scorecol][e]
};                                       // = 107520 B -> 1 block/CU, 8 waves

__global__ __launch_bounds__(512) void k_attn(const float* __restrict__ A,
                                              const unsigned short* __restrict__ WcT,
                                              float* __restrict__ outc,
                                              float* __restrict__ mg,
                                              float* __restrict__ sg) {
    __shared__ SMattn sm;
    int tid = threadIdx.x;
    int chunk = blockIdx.x;
    int e0 = chunk * 64;
    int w = tid >> 6, lane = tid & 63;
    int lr = lane & 15, kg = lane >> 4;

    {   // A prologue: 64x256 fp32 -> bf16 LDS, all 512 threads
        int r = tid >> 3, cg8 = tid & 7;
        const float* ap = &A[(size_t)(e0 + r) * H_DIM + cg8 * 32];
        #pragma unroll
        for (int i = 0; i < 4; ++i) {
            float4 x = *(const float4*)&ap[i * 8];
            float4 y = *(const float4*)&ap[i * 8 + 4];
            uint4 o;
            o.x = pack2(x.x, x.y); o.y = pack2(x.z, x.w);
            o.z = pack2(y.x, y.y); o.w = pack2(y.z, y.w);
            *(uint4*)&sm.As[r][cg8 * 32 + i * 8] = o;
        }
    }
    __syncthreads();                     // barrier 1: As ready

    // wave w owns WcT rows [w*64, w*64+64): w<4 -> V cols, w>=4 -> score cols
    const unsigned short* brow = &WcT[(size_t)(w * 64 + lr) * H_DIM + kg * 8];
    uint4 bfr[2][4];                     // 2-deep k-slice prefetch, 4 ni each
    #pragma unroll
    for (int ni = 0; ni < 4; ++ni) {
        bfr[0][ni] = *(const uint4*)(brow + (size_t)ni * 16 * H_DIM);
        bfr[1][ni] = *(const uint4*)(brow + (size_t)ni * 16 * H_DIM + 32);
    }
    f32x4 acc[4][4] = {};                // [mi][ni] : 64 edges x 64 cols
    #pragma unroll
    for (int k = 0; k < 8; ++k) {
        bf16x8 af[4], bv[4];
        #pragma unroll
        for (int mi = 0; mi < 4; ++mi)
            af[mi] = *(const bf16x8*)&sm.As[mi * 16 + lr][k * 32 + kg * 8];
        #pragma unroll
        for (int ni = 0; ni < 4; ++ni)
            bv[ni] = *(const bf16x8*)&bfr[k & 1][ni];
        if (k < 6) {                     // prefetch k+2 into the slot just freed
            #pragma unroll
            for (int ni = 0; ni < 4; ++ni)
                bfr[k & 1][ni] = *(const uint4*)(brow + (size_t)ni * 16 * H_DIM + (k + 2) * 32);
        }
        #pragma unroll
        for (int mi = 0; mi < 4; ++mi)
            #pragma unroll
            for (int ni = 0; ni < 4; ++ni)
                acc[mi][ni] = __builtin_amdgcn_mfma_f32_16x16x32_bf16(
                    af[mi], bv[ni], acc[mi][ni], 0, 0, 0);
    }

    if (w < 4) {
        // V epilogue: acc(e, d) -> Vt[d][e] bf16   (d = w*64 + ni*16 + lr)
        #pragma unroll
        for (int mi = 0; mi < 4; ++mi)
            #pragma unroll
            for (int ni = 0; ni < 4; ++ni)
                #pragma unroll
                for (int r = 0; r < 4; ++r)
                    sm.Vt[w * 64 + ni * 16 + lr][mi * 16 + kg * 4 + r] =
                        f2bf(acc[mi][ni][r]);
    } else {
        // S epilogue: in-wave column softmax (fp32 scores, bf16 P) + Pt scatter
        int wn = (w - 4) * 64;
        #pragma unroll
        for (int ni = 0; ni < 4; ++ni) {
            float m = -1e30f;
            #pragma unroll
            for (int mi = 0; mi < 4; ++mi)
                #pragma unroll
                for (int r = 0; r < 4; ++r) m = fmaxf(m, acc[mi][ni][r]);
            m = fmaxf(m, __shfl_xor(m, 16, 64));
            m = fmaxf(m, __shfl_xor(m, 32, 64));
            float sv = 0.f;
            #pragma unroll
            for (int mi = 0; mi < 4; ++mi)
                #pragma unroll
                for (int r = 0; r < 4; ++r) {
                    float e_ = __expf(acc[mi][ni][r] - m);
                    unsigned short eb = f2bf(e_);
                    sm.Pt[wn + ni * 16 + lr][mi * 16 + kg * 4 + r] = eb;
                    sv += bf2f(eb);
                }
            sv += __shfl_xor(sv, 16, 64);
            sv += __shfl_xor(sv, 32, 64);
            if (kg == 0) {
                mg[(size_t)chunk * H_DIM + wn + ni * 16 + lr] = m;
                sg[(size_t)chunk * H_DIM + wn + ni * 16 + lr] = sv;
            }
        }
    }
    __syncthreads();                     // barrier 2: Vt + Pt ready

    // PV: wave w -> head w. out(s,d) = sum_e Pt[w*32+s][e] * Vt[w*32+d][e]
    f32x4 acc2[2][2] = {};
    #pragma unroll
    for (int ms = 0; ms < 2; ++ms)
        #pragma unroll
        for (int nd = 0; nd < 2; ++nd)
            #pragma unroll
            for (int kk = 0; kk < 2; ++kk) {
                bf16x8 pa = *(const bf16x8*)&sm.Pt[w * 32 + ms * 16 + lr][kk * 32 + kg * 8];
                bf16x8 vb = *(const bf16x8*)&sm.Vt[w * 32 + nd * 16 + lr][kk * 32 + kg * 8];
                acc2[ms][nd] = __builtin_amdgcn_mfma_f32_16x16x32_bf16(
                    pa, vb, acc2[ms][nd], 0, 0, 0);
            }
    // store chunk partial: outc[chunk][s][h*32+d] fp32  (h = w)
    #pragma unroll
    for (int ms = 0; ms < 2; ++ms)
        #pragma unroll
        for (int nd = 0; nd < 2; ++nd)
            #pragma unroll
            for (int r = 0; r < 4; ++r) {
                int s_ = ms * 16 + kg * 4 + r;
                int c_ = w * 32 + nd * 16 + lr;
                outc[((size_t)chunk * 32 + s_) * H_DIM + c_] = acc2[ms][nd][r];
            }
}

// ---------------- block reduction helper (256 threads = 4 waves) ----------------
__device__ inline float block_sum256(float v, float* red4) {
    for (int o = 32; o > 0; o >>= 1) v += __shfl_xor(v, o, 64);
    int wid = threadIdx.x >> 6;
    if ((threadIdx.x & 63) == 0) red4[wid] = v;
    __syncthreads();
    float r = red4[0] + red4[1] + red4[2] + red4[3];
    __syncthreads();
    return r;
}

// ---------------- K3: flash combine + y = LN(seed + att @ Wo + bo) ----------------
__global__ __launch_bounds__(256) void k_proj_ln(const float* __restrict__ outc,
                                                 const float* __restrict__ mg,
                                                 const float* __restrict__ sg,
                                                 const float* __restrict__ seed,
                                                 const float* __restrict__ Wo,
                                                 const float* __restrict__ bo,
                                                 const float* __restrict__ ln_g,
                                                 const float* __restrict__ ln_b,
                                                 float* __restrict__ Y) {
    int bs0 = blockIdx.x * 4;             // 4 rows, same graph b
    int c = threadIdx.x;
    int b = bs0 >> 5;
    __shared__ float sscale[4][CPG][8];   // exp(m_j - M)/Den per (row, chunk, head)
    __shared__ float arow[4][H_DIM];
    __shared__ float red4[4];
    if (c < 32) {
        int r = c >> 3, hh = c & 7;
        int s_r = (bs0 + r) & 31;
        int sc = hh * 32 + s_r;           // score col for (s,h)
        float mj[CPG];
        float M = -1e30f;
        #pragma unroll
        for (int j = 0; j < CPG; ++j) {
            mj[j] = mg[(size_t)(b * CPG + j) * H_DIM + sc];
            M = fmaxf(M, mj[j]);
        }
        float Den = 0.f;
        #pragma unroll
        for (int j = 0; j < CPG; ++j)
            Den += sg[(size_t)(b * CPG + j) * H_DIM + sc] * __expf(mj[j] - M);
        float inv = 1.f / Den;
        #pragma unroll
        for (int j = 0; j < CPG; ++j)
            sscale[r][j][hh] = __expf(mj[j] - M) * inv;
    }
    __syncthreads();
    int h = c >> 5;
    #pragma unroll
    for (int r = 0; r < 4; ++r) {
        int s_r = (bs0 + r) & 31;
        float a = 0.f;
        #pragma unroll
        for (int j = 0; j < CPG; ++j)
            a = fmaf(outc[((size_t)(b * CPG + j) * 32 + s_r) * H_DIM + c],
                     sscale[r][j][h], a);
        arow[r][c] = a;
    }
    __syncthreads();
    float acc[4];
    float b0 = bo[c];
    #pragma unroll
    for (int r = 0; r < 4; ++r) acc[r] = b0;
    for (int i = 0; i < H_DIM; i += 4) {
        float4 a0 = *(const float4*)&arow[0][i];
        float4 a1 = *(const float4*)&arow[1][i];
        float4 a2 = *(const float4*)&arow[2][i];
        float4 a3 = *(const float4*)&arow[3][i];
        float w0 = Wo[(i + 0) * H_DIM + c], w1 = Wo[(i + 1) * H_DIM + c];
        float w2 = Wo[(i + 2) * H_DIM + c], w3 = Wo[(i + 3) * H_DIM + c];
        acc[0] = fmaf(a0.x, w0, acc[0]); acc[0] = fmaf(a0.y, w1, acc[0]);
        acc[0] = fmaf(a0.z, w2, acc[0]); acc[0] = fmaf(a0.w, w3, acc[0]);
        acc[1] = fmaf(a1.x, w0, acc[1]); acc[1] = fmaf(a1.y, w1, acc[1]);
        acc[1] = fmaf(a1.z, w2, acc[1]); acc[1] = fmaf(a1.w, w3, acc[1]);
        acc[2] = fmaf(a2.x, w0, acc[2]); acc[2] = fmaf(a2.y, w1, acc[2]);
        acc[2] = fmaf(a2.z, w2, acc[2]); acc[2] = fmaf(a2.w, w3, acc[2]);
        acc[3] = fmaf(a3.x, w0, acc[3]); acc[3] = fmaf(a3.y, w1, acc[3]);
        acc[3] = fmaf(a3.z, w2, acc[3]); acc[3] = fmaf(a3.w, w3, acc[3]);
    }
    float g = ln_g[c], be = ln_b[c];
    #pragma unroll
    for (int r = 0; r < 4; ++r) {
        int bs = bs0 + r;
        float y = seed[(bs & 31) * H_DIM + c] + acc[r];
        float mu = block_sum256(y, red4) * (1.f / 256.f);
        float d = y - mu;
        float var = block_sum256(d * d, red4) * (1.f / 256.f);
        Y[(size_t)bs * H_DIM + c] = d * rsqrtf(var + 1e-5f) * g + be;
    }
}

// ---------------- K4: MLP1 partials, W1 read exactly once ----------------
__global__ __launch_bounds__(256) void k_mlp1(const float* __restrict__ Y,
                                              const float* __restrict__ W1,
                                              float* __restrict__ part) {
    int ch = blockIdx.x;          // 128 chunks x 64 rows of W1
    int c = threadIdx.x;
    int i0 = ch * 64;
    __shared__ float fbuf[16][64];
    #pragma unroll
    for (int it = 0; it < 4; ++it) {
        int li = it * 256 + c;
        fbuf[li >> 6][li & 63] = Y[(size_t)(li >> 6) * 8192 + i0 + (li & 63)];
    }
    __syncthreads();
    float acc[16];
    #pragma unroll
    for (int b = 0; b < 16; ++b) acc[b] = 0.f;
    for (int ii = 0; ii < 64; ++ii) {
        float w = W1[(size_t)(i0 + ii) * H_DIM + c];
        #pragma unroll
        for (int b = 0; b < 16; ++b) acc[b] = fmaf(fbuf[b][ii], w, acc[b]);
    }
    #pragma unroll
    for (int b = 0; b < 16; ++b)
        part[((size_t)b * 128 + ch) * H_DIM + c] = acc[b];
}

// ---------------- K5: reduce + SiLU + @W2 + b2 ----------------
__global__ __launch_bounds__(256) void k_mlp2(const float* __restrict__ part,
                                              const float* __restrict__ b1,
                                              const float* __restrict__ W2,
                                              const float* __restrict__ b2,
                                              float* __restrict__ out) {
    int b = blockIdx.x;
    int c = threadIdx.x;
    float s = b1[c];
    const float* pb = &part[(size_t)b * 128 * H_DIM + c];
    #pragma unroll 4
    for (int ch = 0; ch < 128; ++ch) s += pb[(size_t)ch * H_DIM];
    float h1 = s / (1.f + __expf(-s));
    __shared__ float hrow[H_DIM];
    hrow[c] = h1;
    __syncthreads();
    float acc = b2[c];
    for (int j = 0; j < H_DIM; j += 4) {
        float4 hq = *(const float4*)&hrow[j];
        acc = fmaf(hq.x, W2[(j + 0) * H_DIM + c], acc);
        acc = fmaf(hq.y, W2[(j + 1) * H_DIM + c], acc);
        acc = fmaf(hq.z, W2[(j + 2) * H_DIM + c], acc);
        acc = fmaf(hq.w, W2[(j + 3) * H_DIM + c], acc);
    }
    out[(size_t)b * H_DIM + c] = acc;
}

extern "C" void kernel_launch(void* const* d_in, const int* in_sizes, int n_in,
                              void* d_out, int out_size, void* d_ws, size_t ws_size,
                              hipStream_t stream) {
    const float* edge_features = (const float*)d_in[0];
    const float* seed = (const float*)d_in[3];
    const float* Wq   = (const float*)d_in[4];
    const float* Wk   = (const float*)d_in[5];
    const float* Wv   = (const float*)d_in[6];
    const float* Wo   = (const float*)d_in[7];
    const float* bo   = (const float*)d_in[8];
    const float* ln_g = (const float*)d_in[9];
    const float* ln_b = (const float*)d_in[10];
    const float* W1   = (const float*)d_in[11];
    const float* b1   = (const float*)d_in[12];
    const float* W2   = (const float*)d_in[13];
    const float* b2   = (const float*)d_in[14];
    float* out = (float*)d_out;

    // Workspace layout (floats)
    float* ws = (float*)d_ws;
    unsigned short* WcT = (unsigned short*)ws;                    // 512*256 u16 (65536 f)
    float* outc = ws + 65536;                                     // 256*32*256 = 2097152
    float* mg   = outc + 2097152;                                 // 256*256 = 65536
    float* sg   = mg + 65536;                                     // 65536
    float* Y    = sg + 65536;                                     // 131072
    float* part = Y + 131072;                                     // 524288
    // total ~= 2.95M floats ~= 11.8 MB

    k_wc      <<<512, 256, 0, stream>>>(Wv, Wk, Wq, seed, WcT);
    k_attn    <<<NCHUNK, 512, 0, stream>>>(edge_features, WcT, outc, mg, sg);
    k_proj_ln <<<BGRAPHS * S_SEEDS / 4, 256, 0, stream>>>(outc, mg, sg, seed, Wo, bo, ln_g, ln_b, Y);
    k_mlp1    <<<128, 256, 0, stream>>>(Y, W1, part);
    k_mlp2    <<<BGRAPHS, 256, 0, stream>>>(part, b1, W2, b2, out);
}